// Round 4
// baseline (2608.712 us; speedup 1.0000x reference)
//
#include <hip/hip_runtime.h>
#include <hip/hip_bf16.h>

typedef _Float16 half8 __attribute__((ext_vector_type(8)));
typedef float floatx4 __attribute__((ext_vector_type(4)));
typedef float floatx2 __attribute__((ext_vector_type(2)));

#define N_NODES 10000
#define F_NODE  128
#define C_GCN   64
#define N_EDGES 160000
#define T_SEQ   96
#define S_SEQ   32
#define HID     128
#define M_BLK   40          // nodes per block (250 blocks exactly)
#define MT      3           // 3 m-tiles of 16 -> 48 rows (40 real + 8 zero pad)
#define SEQ_STRIDE 104      // 96 + 8 f16 pad (208 B = 13*16)
#define H_STRIDE   136      // 128 + 8 f16 pad (272 B = 17*16)
// per-wave weight streams: L0 waves 14 slots x 4 KB, L1 waves 16 slots x 4 KB
#define L0_STREAM 57344
#define L1_BASE   229376    // 4 * L0_STREAM

// ---------------- fast activations ----------------
__device__ __forceinline__ float fast_rcp(float x) { return __builtin_amdgcn_rcpf(x); }
__device__ __forceinline__ float sigm_f(float x) {
    return fast_rcp(1.0f + __expf(-x));
}
__device__ __forceinline__ float tanh_f(float x) {
    return 2.0f * fast_rcp(1.0f + __expf(-2.0f * x)) - 1.0f;
}

// ---------------- GCN kernels (unchanged) ----------------
__global__ void k_gcn_xw(const float* __restrict__ nf, const float* __restrict__ w,
                         float* __restrict__ xw) {
    int tid = blockIdx.x * 256 + threadIdx.x;
    int n = tid >> 6, c = tid & 63;
    if (n >= N_NODES) return;
    float s = 0.f;
    #pragma unroll 8
    for (int k = 0; k < F_NODE; ++k) s = fmaf(nf[n * F_NODE + k], w[k * C_GCN + c], s);
    xw[n * C_GCN + c] = s;
}

__global__ void k_deg_init(float* __restrict__ deg) {
    int i = blockIdx.x * 256 + threadIdx.x;
    if (i < N_NODES) deg[i] = 1.0f;
}

__global__ void k_deg_count(const int* __restrict__ ei, float* __restrict__ deg) {
    int e = blockIdx.x * 256 + threadIdx.x;
    if (e < N_EDGES) atomicAdd(&deg[ei[N_EDGES + e]], 1.0f);
}

__global__ void k_dinv(const float* __restrict__ deg, float* __restrict__ dinv) {
    int i = blockIdx.x * 256 + threadIdx.x;
    if (i < N_NODES) dinv[i] = rsqrtf(deg[i]);
}

__global__ void k_gcn_self(const float* __restrict__ xw, const float* __restrict__ dinv,
                           const float* __restrict__ gb, float* __restrict__ gout) {
    int tid = blockIdx.x * 256 + threadIdx.x;
    int n = tid >> 6, c = tid & 63;
    if (n >= N_NODES) return;
    float di = dinv[n];
    gout[tid] = xw[tid] * di * di + gb[c];
}

__global__ void k_gcn_scatter(const int* __restrict__ ei, const float* __restrict__ xw,
                              const float* __restrict__ dinv, float* __restrict__ gout) {
    int e = blockIdx.x * 4 + (threadIdx.x >> 6);
    int c = threadIdx.x & 63;
    if (e >= N_EDGES) return;
    int r  = ei[e];
    int cl = ei[N_EDGES + e];
    float nm = dinv[r] * dinv[cl];
    atomicAdd(&gout[cl * C_GCN + c], xw[r * C_GCN + c] * nm);
}

// ---------------- weight packing: group/wave-major streaming order ----------------
// L0 waves w=0..3 own 32 channels (ch0=w*32), stream = 14 slots:
//   s=0..5: IH0 kt=s>>1, n=s&1 (K=96); s=6..13: HH0 kt=(s-6)>>1, n=(s-6)&1 (K=128)
// L1 waves w=4..7 own ch0=(w-4)*32, stream = 16 slots:
//   s=0..7: IH1 kt=s>>1, n=s&1; s=8..15: HH1 kt=(s-8)>>1, n=(s-8)&1 (K=128)
// slot = 4KB = [g:4][lane:64] x half8; lane holds W[g*128+ch0+n*16+(lane&15)][kt*32+(lane>>4)*8+j]
__global__ void k_pack(const float* __restrict__ w_ih0, const float* __restrict__ w_hh0,
                       const float* __restrict__ w_ih1, const float* __restrict__ w_hh1,
                       char* __restrict__ pP) {
    int tid = blockIdx.x * 256 + threadIdx.x;
    if (tid >= 120 * 256) return;
    int lane = tid & 63;
    int g    = (tid >> 6) & 3;
    int gs   = tid >> 8;              // 0..119 global slot
    int w, s, ch0, K, kt, n;
    const float* src;
    size_t base;
    if (gs < 56) {                    // L0 group: 4 waves x 14 slots
        w = gs / 14; s = gs % 14; ch0 = w * 32;
        base = (size_t)w * L0_STREAM;
        if (s < 6) { src = w_ih0; kt = s >> 1;       n = s & 1;       K = 96;  }
        else       { src = w_hh0; kt = (s - 6) >> 1; n = (s - 6) & 1; K = 128; }
    } else {                          // L1 group: 4 waves x 16 slots
        int g2 = gs - 56;
        w = g2 / 16; s = g2 % 16; ch0 = w * 32;
        base = (size_t)L1_BASE + (size_t)w * 65536;
        if (s < 8) { src = w_ih1; kt = s >> 1;       n = s & 1;       K = 128; }
        else       { src = w_hh1; kt = (s - 8) >> 1; n = (s - 8) & 1; K = 128; }
    }
    int row = g * 128 + ch0 + n * 16 + (lane & 15);
    int k0  = kt * 32 + (lane >> 4) * 8;
    half8 v;
    #pragma unroll
    for (int j = 0; j < 8; ++j) v[j] = (_Float16)src[row * K + k0 + j];
    *(half8*)(pP + base + (size_t)s * 4096 + g * 1024 + lane * 16) = v;
}

__global__ void k_bsum(const float* __restrict__ bi0, const float* __restrict__ bh0,
                       const float* __restrict__ bi1, const float* __restrict__ bh1,
                       float* __restrict__ bs) {
    int i = blockIdx.x * 256 + threadIdx.x;
    if (i < 512)       bs[i] = bi0[i] + bh0[i];
    else if (i < 1024) bs[i] = bi1[i - 512] + bh1[i - 512];
}

// ---------------- fused 2-layer LSTM + FC, layer-split wave specialization ----------------
// Waves 0-3: layer 0 at iter u (u = 0..95). Waves 4-7: layer 1 at iter u-1 (u = 1..96).
// Each SIMD hosts one L0 + one L1 wave -> epilogue VALU of one overlaps MFMA of other.
// Weights: global_load_lds, per-iteration-local ring (slot s <-> buffer s%3),
// hand-counted vmcnt (compiler does NOT track LDS-DMA -> LDS-read hazards; round-2 lesson).

__device__ __forceinline__ void async_copy16(const void* g, void* l) {
    __builtin_amdgcn_global_load_lds(
        (const __attribute__((address_space(1))) unsigned int*)g,
        (__attribute__((address_space(3))) unsigned int*)l, 16, 0, 0);
}

__device__ __forceinline__ void dma_slot(const char* __restrict__ src, int lane, _Float16* slot) {
    #pragma unroll
    for (int g = 0; g < 4; ++g)
        async_copy16((const void*)(src + g * 1024 + lane * 16), (void*)(slot + g * 512));
}

#define VMW(N) asm volatile("s_waitcnt vmcnt(" #N ")" ::: "memory")

#define BARRIER_NOVM() do {                                   \
    asm volatile("s_waitcnt lgkmcnt(0)" ::: "memory");        \
    __builtin_amdgcn_s_barrier();                             \
    asm volatile("" ::: "memory");                            \
} while (0)

// load 4 gate-frags of one slot into bg[]
#define LDB(BASE) {                                                         \
    _Pragma("unroll")                                                       \
    for (int g = 0; g < 4; ++g) bg[g] = *(const half8*)((BASE) + g * 512 + lane * 8); }

// 12 MFMAs into acc[.][N][.]
#define MM(N) {                                                             \
    _Pragma("unroll")                                                       \
    for (int g = 0; g < 4; ++g)                                             \
        _Pragma("unroll")                                                   \
        for (int mt = 0; mt < MT; ++mt)                                     \
            acc[g][N][mt] = __builtin_amdgcn_mfma_f32_16x16x32_f16(a[mt], bg[g], acc[g][N][mt], 0, 0, 0); }

// n=0 slot: B frags + fresh A frags; n=1 slot reuses A frags
#define SLOT_N0(BASE, APTR, ASTR, KOFF) { LDB(BASE);                        \
    _Pragma("unroll")                                                       \
    for (int mt = 0; mt < MT; ++mt)                                         \
        a[mt] = *(const half8*)((APTR) + (mt * 16 + l15) * (ASTR) + (KOFF) + quad * 8); \
    MM(0); }
#define SLOT_N1(BASE) { LDB(BASE); MM(1); }

#define DMA2(S, BASE) dma_slot(pWw + (S) * 4096, lane, (BASE))

#define ACCINIT() {                                                         \
    _Pragma("unroll")                                                       \
    for (int g = 0; g < 4; ++g)                                             \
        _Pragma("unroll")                                                   \
        for (int n = 0; n < 2; ++n) {                                       \
            floatx4 bv = {bias[g][n], bias[g][n], bias[g][n], bias[g][n]};  \
            _Pragma("unroll")                                               \
            for (int mt = 0; mt < MT; ++mt) acc[g][n][mt] = bv;             \
        } }

__device__ __forceinline__ void epilogue2(floatx4 acc[4][2][MT], float cst[2][MT][4],
                                          _Float16* H, int quad, int ch0, int l15) {
    #pragma unroll
    for (int n = 0; n < 2; ++n)
        #pragma unroll
        for (int mt = 0; mt < MT; ++mt)
            #pragma unroll
            for (int r = 0; r < 4; ++r) {
                float gi = acc[0][n][mt][r];
                float gf = acc[1][n][mt][r];
                float gg = acc[2][n][mt][r];
                float go = acc[3][n][mt][r];
                float cn = sigm_f(gf) * cst[n][mt][r] + sigm_f(gi) * tanh_f(gg);
                cst[n][mt][r] = cn;
                H[(mt * 16 + quad * 4 + r) * H_STRIDE + ch0 + n * 16 + l15] =
                    (_Float16)(sigm_f(go) * tanh_f(cn));
            }
}

__global__ __launch_bounds__(512, 2) void k_lstm(
    const float* __restrict__ seq, const float* __restrict__ gcn,
    const char* __restrict__ pW, const float* __restrict__ bsum,
    const float* __restrict__ fcw, const float* __restrict__ fcb,
    float* __restrict__ out) {

    __shared__ __align__(16) _Float16 sSeq[48 * SEQ_STRIDE];          //  9,984 B
    __shared__ __align__(16) _Float16 sH0[2][48 * H_STRIDE];          // 26,112 B
    __shared__ __align__(16) _Float16 sH1[2][48 * H_STRIDE];          // 26,112 B
    __shared__ __align__(16) _Float16 sWa[8][2048];                   // 32,768 B
    __shared__ __align__(16) _Float16 sWb[8][2048];                   // 32,768 B
    __shared__ __align__(16) _Float16 sWc[8][2048];                   // 32,768 B  total 160,512 B

    const int tid  = threadIdx.x;
    const int wid  = tid >> 6;
    const int lane = tid & 63;
    const int l15  = lane & 15;
    const int quad = lane >> 4;
    const int node0 = blockIdx.x * M_BLK;
    const bool isL0 = (wid < 4);
    const int ch0 = (wid & 3) * 32;

    _Float16* const rb0 = &sWa[wid][0];
    _Float16* const rb1 = &sWb[wid][0];
    _Float16* const rb2 = &sWc[wid][0];

    const char* pWw = pW + (isL0 ? (size_t)wid * L0_STREAM
                                 : (size_t)L1_BASE + (size_t)(wid - 4) * 65536);

    // zero LDS A-buffers (pad rows stay zero)
    for (int i = tid; i < 48 * SEQ_STRIDE; i += 512) sSeq[i] = (_Float16)0.f;
    for (int i = tid; i < 48 * H_STRIDE; i += 512) {
        sH0[0][i] = (_Float16)0.f; sH0[1][i] = (_Float16)0.f;
        sH1[0][i] = (_Float16)0.f; sH1[1][i] = (_Float16)0.f;
    }

    // biases: own layer only. bias[g][n]
    float bias[4][2];
    {
        int off = isL0 ? 0 : 512;
        #pragma unroll
        for (int g = 0; g < 4; ++g)
            #pragma unroll
            for (int n = 0; n < 2; ++n)
                bias[g][n] = bsum[off + g * 128 + ch0 + n * 16 + l15];
    }

    float cst[2][MT][4] = {{{0}}};

    __syncthreads();

    // stage constant gcn columns (32..95) and seq t=0 (cols 0..31, ALL 40 rows)
    for (int i = tid; i < M_BLK * (C_GCN / 2); i += 512) {
        int r = i >> 5, cp = (i & 31) * 2;
        floatx2 v = *(const floatx2*)(gcn + (size_t)(node0 + r) * C_GCN + cp);
        sSeq[r * SEQ_STRIDE + S_SEQ + cp]     = (_Float16)v.x;
        sSeq[r * SEQ_STRIDE + S_SEQ + cp + 1] = (_Float16)v.y;
    }
    {
        int r = tid >> 4, cp = (tid & 15) * 2;
        floatx2 v = *(const floatx2*)(seq + ((size_t)(node0 + r) * T_SEQ) * S_SEQ + cp);
        sSeq[r * SEQ_STRIDE + cp]     = (_Float16)v.x;
        sSeq[r * SEQ_STRIDE + cp + 1] = (_Float16)v.y;
        if (tid < 128) {
            int r2 = (512 + tid) >> 4;
            floatx2 w = *(const floatx2*)(seq + ((size_t)(node0 + r2) * T_SEQ) * S_SEQ + cp);
            sSeq[r2 * SEQ_STRIDE + cp]     = (_Float16)w.x;
            sSeq[r2 * SEQ_STRIDE + cp + 1] = (_Float16)w.y;
        }
    }
    __syncthreads();   // full drain once at setup is fine

    // seq prefetch state (L1 waves only): issue seq(u+2) at iter u, commit seq(u+1) post-B1
    const int tid2 = tid & 255;               // 0..255 within group
    const int pr0 = tid2 >> 4, pcp = (tid2 & 15) * 2;
    floatx2 pfa = {0.f, 0.f}, pfb = {0.f, 0.f}, pfc = {0.f, 0.f};

#define PF_ISSUE(T) do { if ((T) <= 95) {                                               \
        pfa = *(const floatx2*)(seq + ((size_t)(node0 + pr0)      * T_SEQ + (T)) * S_SEQ + pcp); \
        pfb = *(const floatx2*)(seq + ((size_t)(node0 + pr0 + 16) * T_SEQ + (T)) * S_SEQ + pcp); \
        if (tid2 < 128)                                                                 \
        pfc = *(const floatx2*)(seq + ((size_t)(node0 + pr0 + 32) * T_SEQ + (T)) * S_SEQ + pcp); \
    } } while (0)

#define COMMIT_SEQ() do { if (u < 95) {                                                 \
        sSeq[pr0 * SEQ_STRIDE + pcp]            = (_Float16)pfa.x;                      \
        sSeq[pr0 * SEQ_STRIDE + pcp + 1]        = (_Float16)pfa.y;                      \
        sSeq[(pr0 + 16) * SEQ_STRIDE + pcp]     = (_Float16)pfb.x;                      \
        sSeq[(pr0 + 16) * SEQ_STRIDE + pcp + 1] = (_Float16)pfb.y;                      \
        if (tid2 < 128) {                                                               \
            sSeq[(pr0 + 32) * SEQ_STRIDE + pcp]     = (_Float16)pfc.x;                  \
            sSeq[(pr0 + 32) * SEQ_STRIDE + pcp + 1] = (_Float16)pfc.y;                  \
        } } } while (0)

    // prologue: pf seq(1) (L1), then slots 0,1 of each wave's own stream in flight
    if (!isL0) PF_ISSUE(1);
    DMA2(0, rb0);
    DMA2(1, rb1);

    floatx4 acc[4][2][MT];
    half8 a[MT], bg[4];

    for (int u = 0; u < 96; ++u) {
        const int wp = u & 1, rp = wp ^ 1;

        if (isL0) {
            // ---- layer 0, step u: gates = IH0*seq(u) + HH0*h0(u-1) ----
            const _Float16* h0r = &sH0[rp][0];
            _Float16*       h0w = &sH0[wp][0];
            ACCINIT();
            DMA2(2, rb2);  VMW(8); SLOT_N0(rb0, sSeq, SEQ_STRIDE, 0);    // s0
            DMA2(3, rb0);  VMW(8); SLOT_N1(rb1);                         // s1
            DMA2(4, rb1);  VMW(8); SLOT_N0(rb2, sSeq, SEQ_STRIDE, 32);   // s2
            DMA2(5, rb2);  VMW(8); SLOT_N1(rb0);                         // s3
            DMA2(6, rb0);  VMW(8); SLOT_N0(rb1, sSeq, SEQ_STRIDE, 64);   // s4
            DMA2(7, rb1);  VMW(8); SLOT_N1(rb2);                         // s5
            BARRIER_NOVM();   // B1: sSeq reads done -> L1 may commit seq(u+1)
            DMA2(8, rb2);  VMW(8); SLOT_N0(rb0, h0r, H_STRIDE, 0);       // s6
            DMA2(9, rb0);  VMW(8); SLOT_N1(rb1);                         // s7
            DMA2(10, rb1); VMW(8); SLOT_N0(rb2, h0r, H_STRIDE, 32);      // s8
            DMA2(11, rb2); VMW(8); SLOT_N1(rb0);                         // s9
            DMA2(12, rb0); VMW(8); SLOT_N0(rb1, h0r, H_STRIDE, 64);      // s10
            DMA2(13, rb1); VMW(8); SLOT_N1(rb2);                         // s11
            VMW(4); SLOT_N0(rb0, h0r, H_STRIDE, 96); DMA2(0, rb0);       // s12 (+pf next s0)
            VMW(4); SLOT_N1(rb1);                    DMA2(1, rb1);       // s13 (+pf next s1)
            epilogue2(acc, cst, h0w, quad, ch0, l15);
            BARRIER_NOVM();   // B2: h0(u) visible
        } else {
            // ---- layer 1, step u-1: gates = IH1*h0(u-1) + HH1*h1(u-2) ----
            const _Float16* h0r = &sH0[rp][0];
            const _Float16* h1r = &sH1[wp][0];
            _Float16*       h1w = &sH1[rp][0];
            ACCINIT();
            DMA2(2, rb2);  VMW(4); SLOT_N0(rb0, h0r, H_STRIDE, 0);       // s0
            DMA2(3, rb0);  VMW(8); SLOT_N1(rb1);                         // s1
            DMA2(4, rb1);  VMW(8); SLOT_N0(rb2, h0r, H_STRIDE, 32);      // s2
            DMA2(5, rb2);  VMW(8); SLOT_N1(rb0);                         // s3
            DMA2(6, rb0);  VMW(8); SLOT_N0(rb1, h0r, H_STRIDE, 64);      // s4
            DMA2(7, rb1);  VMW(8); SLOT_N1(rb2);                         // s5
            DMA2(8, rb2);  VMW(8); SLOT_N0(rb0, h0r, H_STRIDE, 96);      // s6
            DMA2(9, rb0);  VMW(8); SLOT_N1(rb1);                         // s7
            BARRIER_NOVM();   // B1
            COMMIT_SEQ();     // seq(u+1) -> sSeq (L0's reads are done)
            DMA2(10, rb1); VMW(8); SLOT_N0(rb2, h1r, H_STRIDE, 0);       // s8
            DMA2(11, rb2); VMW(8); SLOT_N1(rb0);                         // s9
            DMA2(12, rb0); VMW(8); SLOT_N0(rb1, h1r, H_STRIDE, 32);      // s10
            DMA2(13, rb1); VMW(8); SLOT_N1(rb2);                         // s11
            DMA2(14, rb2); VMW(8); SLOT_N0(rb0, h1r, H_STRIDE, 64);      // s12
            DMA2(15, rb0); VMW(8); SLOT_N1(rb1);                         // s13
            DMA2(1, rb1);  VMW(8); SLOT_N0(rb2, h1r, H_STRIDE, 96);      // s14 (+pf next s1)
            VMW(4); SLOT_N1(rb0); PF_ISSUE(u + 2); DMA2(0, rb0);         // s15 (+pf next s0)
            if (u) epilogue2(acc, cst, h1w, quad, ch0, l15);   // h1(u-1); skip garbage at u=0
            BARRIER_NOVM();   // B2
        }
    }

    // ---- tail iteration u=96: layer 1 computes h1(95) ----
    if (!isL0) {
        const _Float16* h0r = &sH0[1][0];   // h0(95)
        const _Float16* h1r = &sH1[0][0];   // h1(94)
        _Float16*       h1w = &sH1[1][0];   // h1(95)
        ACCINIT();
        DMA2(2, rb2);  VMW(4); SLOT_N0(rb0, h0r, H_STRIDE, 0);
        DMA2(3, rb0);  VMW(8); SLOT_N1(rb1);
        DMA2(4, rb1);  VMW(8); SLOT_N0(rb2, h0r, H_STRIDE, 32);
        DMA2(5, rb2);  VMW(8); SLOT_N1(rb0);
        DMA2(6, rb0);  VMW(8); SLOT_N0(rb1, h0r, H_STRIDE, 64);
        DMA2(7, rb1);  VMW(8); SLOT_N1(rb2);
        DMA2(8, rb2);  VMW(8); SLOT_N0(rb0, h0r, H_STRIDE, 96);
        DMA2(9, rb0);  VMW(8); SLOT_N1(rb1);
        DMA2(10, rb1); VMW(8); SLOT_N0(rb2, h1r, H_STRIDE, 0);
        DMA2(11, rb2); VMW(8); SLOT_N1(rb0);
        DMA2(12, rb0); VMW(8); SLOT_N0(rb1, h1r, H_STRIDE, 32);
        DMA2(13, rb1); VMW(8); SLOT_N1(rb2);
        DMA2(14, rb2); VMW(8); SLOT_N0(rb0, h1r, H_STRIDE, 64);
        DMA2(15, rb0); VMW(8); SLOT_N1(rb1);
        VMW(4); SLOT_N0(rb2, h1r, H_STRIDE, 96);
        VMW(0); SLOT_N1(rb0);
        epilogue2(acc, cst, h1w, quad, ch0, l15);
    }
    asm volatile("s_waitcnt vmcnt(0)" ::: "memory");   // drain leftover prefetch DMAs
    __syncthreads();

    // FC on h1(95) = sH1[1]
    if (tid < M_BLK) {
        const _Float16* h1 = &sH1[1][tid * H_STRIDE];
        float s = fcb[0];
        #pragma unroll 16
        for (int k = 0; k < HID; ++k) s = fmaf((float)h1[k], fcw[k], s);
        out[node0 + tid] = s;
    }
}

// ---------------- launch ----------------
extern "C" void kernel_launch(void* const* d_in, const int* in_sizes, int n_in,
                              void* d_out, int out_size, void* d_ws, size_t ws_size,
                              hipStream_t stream) {
    const float* seq   = (const float*)d_in[0];
    const int*   ei    = (const int*)d_in[1];
    const float* nf    = (const float*)d_in[3];
    const float* gcn_w = (const float*)d_in[5];
    const float* gcn_b = (const float*)d_in[6];
    const float* w_ih0 = (const float*)d_in[7];
    const float* w_hh0 = (const float*)d_in[8];
    const float* b_ih0 = (const float*)d_in[9];
    const float* b_hh0 = (const float*)d_in[10];
    const float* w_ih1 = (const float*)d_in[11];
    const float* w_hh1 = (const float*)d_in[12];
    const float* b_ih1 = (const float*)d_in[13];
    const float* b_hh1 = (const float*)d_in[14];
    const float* fc_w  = (const float*)d_in[15];
    const float* fc_b  = (const float*)d_in[16];
    float* out = (float*)d_out;

    char* ws = (char*)d_ws;
    float* xw   = (float*)(ws);                    // 2,560,000 B
    float* gout = (float*)(ws + 2621440);          // 2,560,000 B
    float* deg  = (float*)(ws + 5242880);          // 40,000 B
    float* dinv = (float*)(ws + 5283840);          // 40,000 B
    float* bsum = (float*)(ws + 5324800);          // 4,096 B
    char*  pP   = (char*)(ws + 5328896);           // 491,520 B

    // GCN (fp32 exact)
    k_gcn_xw     <<<2500,  256, 0, stream>>>(nf, gcn_w, xw);
    k_deg_init   <<<40,    256, 0, stream>>>(deg);
    k_deg_count  <<<625,   256, 0, stream>>>(ei, deg);
    k_dinv       <<<40,    256, 0, stream>>>(deg, dinv);
    k_gcn_self   <<<2500,  256, 0, stream>>>(xw, dinv, gcn_b, gout);
    k_gcn_scatter<<<40000, 256, 0, stream>>>(ei, xw, dinv, gout);

    // weight prep (group/wave-major streaming layout)
    k_pack<<<120, 256, 0, stream>>>(w_ih0, w_hh0, w_ih1, w_hh1, pP);
    k_bsum<<<4,   256, 0, stream>>>(b_ih0, b_hh0, b_ih1, b_hh1, bsum);

    // fused 2-layer LSTM + FC (layer-split wave specialization)
    k_lstm<<<250, 512, 0, stream>>>(seq, gout, pP, bsum, fc_w, fc_b, out);
}

// Round 5
// 1250.057 us; speedup vs baseline: 2.0869x; 2.0869x over previous
//
#include <hip/hip_runtime.h>
#include <hip/hip_bf16.h>

typedef _Float16 half8 __attribute__((ext_vector_type(8)));
typedef float floatx4 __attribute__((ext_vector_type(4)));
typedef float floatx2 __attribute__((ext_vector_type(2)));

#define N_NODES 10000
#define F_NODE  128
#define C_GCN   64
#define N_EDGES 160000
#define T_SEQ   96
#define S_SEQ   32
#define HID     128
#define M_BLK   40          // nodes per block (250 blocks exactly)
#define MT      3           // 3 m-tiles of 16 -> 48 rows (40 real + 8 zero pad)
#define SEQ_STRIDE 104      // 96 + 8 f16 pad (208 B = 13*16)
#define H_STRIDE   136      // 128 + 8 f16 pad (272 B = 17*16)
#define WAVE_STREAM 61440   // bytes of packed weights per wave per step (15 slots x 4 KB)

// ---------------- fast activations: native v_exp_f32 + v_rcp_f32 ----------------
__device__ __forceinline__ float fast_rcp(float x) { return __builtin_amdgcn_rcpf(x); }
__device__ __forceinline__ float sigm_f(float x) {
    return fast_rcp(1.0f + __expf(-x));
}
__device__ __forceinline__ float tanh_f(float x) {
    return 2.0f * fast_rcp(1.0f + __expf(-2.0f * x)) - 1.0f;
}

// ---------------- GCN kernels (all fp32, tiny) ----------------
__global__ void k_gcn_xw(const float* __restrict__ nf, const float* __restrict__ w,
                         float* __restrict__ xw) {
    int tid = blockIdx.x * 256 + threadIdx.x;
    int n = tid >> 6, c = tid & 63;
    if (n >= N_NODES) return;
    float s = 0.f;
    #pragma unroll 8
    for (int k = 0; k < F_NODE; ++k) s = fmaf(nf[n * F_NODE + k], w[k * C_GCN + c], s);
    xw[n * C_GCN + c] = s;
}

__global__ void k_deg_init(float* __restrict__ deg) {
    int i = blockIdx.x * 256 + threadIdx.x;
    if (i < N_NODES) deg[i] = 1.0f;   // self loop
}

__global__ void k_deg_count(const int* __restrict__ ei, float* __restrict__ deg) {
    int e = blockIdx.x * 256 + threadIdx.x;
    if (e < N_EDGES) atomicAdd(&deg[ei[N_EDGES + e]], 1.0f);
}

__global__ void k_dinv(const float* __restrict__ deg, float* __restrict__ dinv) {
    int i = blockIdx.x * 256 + threadIdx.x;
    if (i < N_NODES) dinv[i] = rsqrtf(deg[i]);
}

__global__ void k_gcn_self(const float* __restrict__ xw, const float* __restrict__ dinv,
                           const float* __restrict__ gb, float* __restrict__ gout) {
    int tid = blockIdx.x * 256 + threadIdx.x;
    int n = tid >> 6, c = tid & 63;
    if (n >= N_NODES) return;
    float di = dinv[n];
    gout[tid] = xw[tid] * di * di + gb[c];
}

__global__ void k_gcn_scatter(const int* __restrict__ ei, const float* __restrict__ xw,
                              const float* __restrict__ dinv, float* __restrict__ gout) {
    int e = blockIdx.x * 4 + (threadIdx.x >> 6);
    int c = threadIdx.x & 63;
    if (e >= N_EDGES) return;
    int r  = ei[e];
    int cl = ei[N_EDGES + e];
    float nm = dinv[r] * dinv[cl];
    atomicAdd(&gout[cl * C_GCN + c], xw[r * C_GCN + c] * nm);
}

// ---------------- weight packing: wave-major streaming order (round-3 layout) ----------------
__global__ void k_pack(const float* __restrict__ w_ih0, const float* __restrict__ w_hh0,
                       const float* __restrict__ w_ih1, const float* __restrict__ w_hh1,
                       half8* __restrict__ pP) {
    int tid = blockIdx.x * 256 + threadIdx.x;
    if (tid >= 8 * 15 * 4 * 64) return;
    int lane = tid & 63;
    int g    = (tid >> 6) & 3;
    int s    = (tid >> 8) % 15;
    int w    = tid / 3840;
    const float* src; int kt, K;
    if (s < 3)       { src = w_ih0; kt = s;      K = 96;  }
    else if (s < 7)  { src = w_hh0; kt = s - 3;  K = 128; }
    else if (s < 11) { src = w_ih1; kt = s - 7;  K = 128; }
    else             { src = w_hh1; kt = s - 11; K = 128; }
    int row = g * 128 + w * 16 + (lane & 15);
    int k0  = kt * 32 + (lane >> 4) * 8;
    half8 v;
    #pragma unroll
    for (int j = 0; j < 8; ++j) v[j] = (_Float16)src[row * K + k0 + j];
    pP[tid] = v;
}

__global__ void k_bsum(const float* __restrict__ bi0, const float* __restrict__ bh0,
                       const float* __restrict__ bi1, const float* __restrict__ bh1,
                       float* __restrict__ bs) {
    int i = blockIdx.x * 256 + threadIdx.x;
    if (i < 512)       bs[i] = bi0[i] + bh0[i];
    else if (i < 1024) bs[i] = bi1[i - 512] + bh1[i - 512];
}

// ---------------- fused 2-layer LSTM + FC ----------------
// Round-3 structure + in-wave software pipeline:
//   slot s: DMA(s+2) -> counted VMW -> ds_read B(s+1)/A(s+1) into ALT reg set
//           -> MFMA(s) on the set loaded last slot.
// ds_read latency hides under MFMA issue; DMA stays 2 slots ahead; barriers
// never drain vmcnt. All waits hand-counted (compiler can't track LDS-DMA).

__device__ __forceinline__ void async_copy16(const void* g, void* l) {
    __builtin_amdgcn_global_load_lds(
        (const __attribute__((address_space(1))) unsigned int*)g,
        (__attribute__((address_space(3))) unsigned int*)l, 16, 0, 0);
}

__device__ __forceinline__ void dma_slot(const char* __restrict__ src, int lane, _Float16* slot) {
    #pragma unroll
    for (int g = 0; g < 4; ++g)
        async_copy16((const void*)(src + g * 1024 + lane * 16), (void*)(slot + g * 512));
}

#define VMW(N) asm volatile("s_waitcnt vmcnt(" #N ")" ::: "memory")

#define BARRIER_NOVM() do {                                   \
    asm volatile("s_waitcnt lgkmcnt(0)" ::: "memory");        \
    __builtin_amdgcn_s_barrier();                             \
    asm volatile("" ::: "memory");                            \
} while (0)

// read 4 B-gate frags of one LDS slot into a register set
#define RDB(BG, BUF) {                                                      \
    _Pragma("unroll")                                                       \
    for (int g = 0; g < 4; ++g) (BG)[g] = *(const half8*)((BUF) + g * 512 + lane * 8); }

// read 3 A frags into a register set
#define RDA(AA, APTR, KOFF, ASTR) {                                         \
    _Pragma("unroll")                                                       \
    for (int mt = 0; mt < MT; ++mt)                                         \
        (AA)[mt] = *(const half8*)((APTR) + (mt * 16 + l15) * (ASTR) + (KOFF) + quad * 8); }

// 12 MFMAs on a loaded set
#define MM(AA, BG) {                                                        \
    _Pragma("unroll")                                                       \
    for (int g = 0; g < 4; ++g)                                             \
        _Pragma("unroll")                                                   \
        for (int mt = 0; mt < MT; ++mt)                                     \
            acc[g][mt] = __builtin_amdgcn_mfma_f32_16x16x32_f16((AA)[mt], (BG)[g], acc[g][mt], 0, 0, 0); }

#define ACCINIT(B) {                                                        \
    _Pragma("unroll")                                                       \
    for (int g = 0; g < 4; ++g) {                                           \
        floatx4 bv = {(B)[g], (B)[g], (B)[g], (B)[g]};                      \
        _Pragma("unroll")                                                   \
        for (int mt = 0; mt < MT; ++mt) acc[g][mt] = bv;                    \
    } }

__device__ __forceinline__ void epilogue(floatx4 acc[4][MT],
                                         float c[MT][4], _Float16* Hnext,
                                         int quad, int ch) {
    #pragma unroll
    for (int mt = 0; mt < MT; ++mt) {
        #pragma unroll
        for (int r = 0; r < 4; ++r) {
            float gi = acc[0][mt][r];
            float gf = acc[1][mt][r];
            float gg = acc[2][mt][r];
            float go = acc[3][mt][r];
            float cn = sigm_f(gf) * c[mt][r] + sigm_f(gi) * tanh_f(gg);
            c[mt][r] = cn;
            float h = sigm_f(go) * tanh_f(cn);
            Hnext[(mt * 16 + quad * 4 + r) * H_STRIDE + ch] = (_Float16)h;
        }
    }
}

__global__ __launch_bounds__(512, 2) void k_lstm(
    const float* __restrict__ seq, const float* __restrict__ gcn,
    const char* __restrict__ pW, const float* __restrict__ bsum,
    const float* __restrict__ fcw, const float* __restrict__ fcb,
    float* __restrict__ out) {

    __shared__ __align__(16) _Float16 sSeq[48 * SEQ_STRIDE];          //  9,984 B
    __shared__ __align__(16) _Float16 sH0[2][48 * H_STRIDE];          // 26,112 B
    __shared__ __align__(16) _Float16 sH1[2][48 * H_STRIDE];          // 26,112 B
    __shared__ __align__(16) _Float16 sWa[8][2048];                   // 32,768 B
    __shared__ __align__(16) _Float16 sWb[8][2048];                   // 32,768 B
    __shared__ __align__(16) _Float16 sWc[8][2048];                   // 32,768 B  total 160,512 B

    const int tid  = threadIdx.x;
    const int wid  = tid >> 6;
    const int lane = tid & 63;
    const int l15  = lane & 15;
    const int quad = lane >> 4;
    const int node0 = blockIdx.x * M_BLK;
    const int ch = wid * 16 + l15;

    _Float16* const rb0 = &sWa[wid][0];
    _Float16* const rb1 = &sWb[wid][0];
    _Float16* const rb2 = &sWc[wid][0];

    const char* pWw = pW + wid * WAVE_STREAM;

#define DMA(S, RB) dma_slot(pWw + (S) * 4096, lane, (RB))

    // prologue DMA: slots 0,1 in flight during setup
    DMA(0, rb0);
    DMA(1, rb1);

    // zero LDS A-buffers (pad rows 40..47 stay zero forever)
    for (int i = tid; i < 48 * SEQ_STRIDE; i += 512) sSeq[i] = (_Float16)0.f;
    for (int i = tid; i < 48 * H_STRIDE; i += 512) {
        sH0[0][i] = (_Float16)0.f; sH0[1][i] = (_Float16)0.f;
        sH1[0][i] = (_Float16)0.f; sH1[1][i] = (_Float16)0.f;
    }

    float bias0[4], bias1[4];
    #pragma unroll
    for (int g = 0; g < 4; ++g) {
        bias0[g] = bsum[g * 128 + ch];
        bias1[g] = bsum[512 + g * 128 + ch];
    }

    float c0[MT][4] = {{0}}, c1[MT][4] = {{0}};

    __syncthreads();   // setup barrier (full drain; prologue DMAs complete here)

    // stage constant gcn columns (32..95) and seq t=0 (cols 0..31)
    for (int i = tid; i < M_BLK * (C_GCN / 2); i += 512) {
        int r = i >> 5, cp = (i & 31) * 2;
        floatx2 v = *(const floatx2*)(gcn + (size_t)(node0 + r) * C_GCN + cp);
        sSeq[r * SEQ_STRIDE + S_SEQ + cp]     = (_Float16)v.x;
        sSeq[r * SEQ_STRIDE + S_SEQ + cp + 1] = (_Float16)v.y;
    }
    {
        int r = tid >> 4, cp = (tid & 15) * 2;
        if (tid < M_BLK * 16) {
            floatx2 v = *(const floatx2*)(seq + ((size_t)(node0 + r) * T_SEQ) * S_SEQ + cp);
            sSeq[r * SEQ_STRIDE + cp]     = (_Float16)v.x;
            sSeq[r * SEQ_STRIDE + cp + 1] = (_Float16)v.y;
        }
    }
    __syncthreads();   // setup barrier (drains; loop counts start from empty queue)

    floatx4 acc[4][MT];
    half8 aX[MT], aY[MT], bX[4], bY[4];

    // preload B(0) fragments (DMA(0) already drained by the syncthreads)
    RDB(bX, rb0);

    // seq prefetch: every wave issues EXACTLY 2 loads per step (uniform vmcnt counts).
    // rows 0..31 by all 512 threads; rows 32..39 duplicated 4x, committed by tid<128.
    const int pr = tid >> 4, pc = (tid & 15) * 2;
    const int r1 = 32 + ((tid & 127) >> 4);
    floatx2 pfa, pfb;

    for (int t = 0; t < T_SEQ; ++t) {
        const int cur = t & 1, nxt = cur ^ 1;
        const _Float16* h0c = &sH0[cur][0];
        _Float16*       h0n = &sH0[nxt][0];
        const _Float16* h1c = &sH1[cur][0];
        _Float16*       h1n = &sH1[nxt][0];

        // pf seq(t+1) — unconditional (clamped) so the vm queue is step-invariant
        {
            int tp = (t + 1 < T_SEQ) ? (t + 1) : (T_SEQ - 1);
            pfa = *(const floatx2*)(seq + ((size_t)(node0 + pr) * T_SEQ + tp) * S_SEQ + pc);
            pfb = *(const floatx2*)(seq + ((size_t)(node0 + r1) * T_SEQ + tp) * S_SEQ + pc);
        }

        // ---- phase A: slots 0..6 (0..2: sSeq x IH0, 3..6: h0c x HH0) ----
        ACCINIT(bias0);
        RDA(aX, sSeq, 0, SEQ_STRIDE);                                     // A(0), exposed once
        // queue entering slot 0: [D1':4][pf:2][D2:4] -> VMW(6) completes D1'
        DMA(2, rb2);  VMW(6); RDB(bY, rb1); RDA(aY, sSeq, 32, SEQ_STRIDE); MM(aX, bX);  // s0
        DMA(3, rb0);  VMW(4); RDB(bX, rb2); RDA(aX, sSeq, 64, SEQ_STRIDE); MM(aY, bY);  // s1
        DMA(4, rb1);  VMW(4); RDB(bY, rb0); RDA(aY, h0c, 0,  H_STRIDE);    MM(aX, bX);  // s2
        DMA(5, rb2);  VMW(4); RDB(bX, rb1); RDA(aX, h0c, 32, H_STRIDE);    MM(aY, bY);  // s3
        DMA(6, rb0);  VMW(4); RDB(bY, rb2); RDA(aY, h0c, 64, H_STRIDE);    MM(aX, bX);  // s4
        DMA(7, rb1);  VMW(4); RDB(bX, rb0); RDA(aX, h0c, 96, H_STRIDE);    MM(aY, bY);  // s5
        DMA(8, rb2);  VMW(4); RDB(bY, rb1);                                MM(aX, bX);  // s6 (no A-pf across barrier)
        epilogue(acc, c0, h0n, quad, ch);
        BARRIER_NOVM();   // h0(t) visible; weight DMAs stay in flight

        // ---- phase B: slots 7..14 (7..10: h0n x IH1, 11..14: h1c x HH1) ----
        ACCINIT(bias1);
        RDA(aY, h0n, 0, H_STRIDE);                                        // A(7), exposed once
        DMA(9,  rb0); VMW(4); RDB(bX, rb2); RDA(aX, h0n, 32, H_STRIDE); MM(aY, bY);  // s7
        DMA(10, rb1); VMW(4); RDB(bY, rb0); RDA(aY, h0n, 64, H_STRIDE); MM(aX, bX);  // s8
        DMA(11, rb2); VMW(4); RDB(bX, rb1); RDA(aX, h0n, 96, H_STRIDE); MM(aY, bY);  // s9
        DMA(12, rb0); VMW(4); RDB(bY, rb2); RDA(aY, h1c, 0,  H_STRIDE); MM(aX, bX);  // s10
        DMA(13, rb1); VMW(4); RDB(bX, rb0); RDA(aX, h1c, 32, H_STRIDE); MM(aY, bY);  // s11
        DMA(14, rb2); VMW(4); RDB(bY, rb1); RDA(aY, h1c, 64, H_STRIDE); MM(aX, bX);  // s12
        DMA(0,  rb0); VMW(4); RDB(bX, rb2); RDA(aX, h1c, 96, H_STRIDE); MM(aY, bY);  // s13 (DMA wraps)
        DMA(1,  rb1); VMW(4); MM(aX, bX);   RDB(bX, rb0);                            // s14: MFMA first, then B(0') into bX

        // commit seq(t+1) from prefetch regs (phase-A readers of sSeq are done)
        if (t + 1 < T_SEQ) {
            sSeq[pr * SEQ_STRIDE + pc]     = (_Float16)pfa.x;
            sSeq[pr * SEQ_STRIDE + pc + 1] = (_Float16)pfa.y;
            if (tid < 128) {
                sSeq[r1 * SEQ_STRIDE + pc]     = (_Float16)pfb.x;
                sSeq[r1 * SEQ_STRIDE + pc + 1] = (_Float16)pfb.y;
            }
        }
        epilogue(acc, c1, h1n, quad, ch);
        BARRIER_NOVM();   // h1(t) + seq(t+1) visible
    }

#undef DMA

    // drain the tail DMAs (slots 0/1 prefetched for the nonexistent step 96)
    asm volatile("s_waitcnt vmcnt(0)" ::: "memory");

    // final h1 lives in buffer (T_SEQ & 1) == 0
    if (tid < M_BLK) {
        const _Float16* h1 = &sH1[0][tid * H_STRIDE];
        float s = fcb[0];
        #pragma unroll 16
        for (int k = 0; k < HID; ++k) s = fmaf((float)h1[k], fcw[k], s);
        out[node0 + tid] = s;
    }
}

// ---------------- launch ----------------
extern "C" void kernel_launch(void* const* d_in, const int* in_sizes, int n_in,
                              void* d_out, int out_size, void* d_ws, size_t ws_size,
                              hipStream_t stream) {
    const float* seq   = (const float*)d_in[0];
    const int*   ei    = (const int*)d_in[1];     // int64 in reference -> int32 on device
    const float* nf    = (const float*)d_in[3];
    const float* gcn_w = (const float*)d_in[5];
    const float* gcn_b = (const float*)d_in[6];
    const float* w_ih0 = (const float*)d_in[7];
    const float* w_hh0 = (const float*)d_in[8];
    const float* b_ih0 = (const float*)d_in[9];
    const float* b_hh0 = (const float*)d_in[10];
    const float* w_ih1 = (const float*)d_in[11];
    const float* w_hh1 = (const float*)d_in[12];
    const float* b_ih1 = (const float*)d_in[13];
    const float* b_hh1 = (const float*)d_in[14];
    const float* fc_w  = (const float*)d_in[15];
    const float* fc_b  = (const float*)d_in[16];
    float* out = (float*)d_out;

    char* ws = (char*)d_ws;
    float* xw   = (float*)(ws);                    // 2,560,000 B
    float* gout = (float*)(ws + 2621440);          // 2,560,000 B
    float* deg  = (float*)(ws + 5242880);          // 40,000 B
    float* dinv = (float*)(ws + 5283840);          // 40,000 B
    float* bsum = (float*)(ws + 5324800);          // 4,096 B
    char*  pP   = (char*)(ws + 5328896);           // 491,520 B

    // GCN (fp32 exact)
    k_gcn_xw     <<<2500,  256, 0, stream>>>(nf, gcn_w, xw);
    k_deg_init   <<<40,    256, 0, stream>>>(deg);
    k_deg_count  <<<625,   256, 0, stream>>>(ei, deg);
    k_dinv       <<<40,    256, 0, stream>>>(deg, dinv);
    k_gcn_self   <<<2500,  256, 0, stream>>>(xw, dinv, gcn_b, gout);
    k_gcn_scatter<<<40000, 256, 0, stream>>>(ei, xw, dinv, gout);

    // weight prep (wave-major streaming layout)
    k_pack<<<120, 256, 0, stream>>>(w_ih0, w_hh0, w_ih1, w_hh1, (half8*)pP);
    k_bsum<<<4,   256, 0, stream>>>(b_ih0, b_hh0, b_ih1, b_hh1, bsum);

    // fused 2-layer LSTM + FC
    k_lstm<<<250, 512, 0, stream>>>(seq, gout, pP, bsum, fc_w, fc_b, out);
}

// Round 6
// 1160.375 us; speedup vs baseline: 2.2482x; 1.0773x over previous
//
#include <hip/hip_runtime.h>
#include <hip/hip_bf16.h>

typedef _Float16 half8 __attribute__((ext_vector_type(8)));
typedef float floatx4 __attribute__((ext_vector_type(4)));
typedef float floatx2 __attribute__((ext_vector_type(2)));

#define N_NODES 10000
#define F_NODE  128
#define C_GCN   64
#define N_EDGES 160000
#define T_SEQ   96
#define S_SEQ   32
#define HID     128
#define M_BLK   40          // nodes per block (250 blocks exactly)
#define MT      3           // 3 m-tiles of 16 -> 48 rows (40 real + 8 zero pad)
#define SEQ_STRIDE 104      // 96 + 8 f16 pad (208 B = 13*16)
#define H_STRIDE   136      // 128 + 8 f16 pad (272 B = 17*16)
#define WAVE_STREAM 61440   // bytes of packed weights per wave per step (15 slots x 4 KB)

// ---------------- fast activations: native v_exp_f32 + v_rcp_f32 ----------------
__device__ __forceinline__ float fast_rcp(float x) { return __builtin_amdgcn_rcpf(x); }
__device__ __forceinline__ float sigm_f(float x) {
    return fast_rcp(1.0f + __expf(-x));
}
__device__ __forceinline__ float tanh_f(float x) {
    return 2.0f * fast_rcp(1.0f + __expf(-2.0f * x)) - 1.0f;
}

// ---------------- GCN kernels (all fp32, tiny) ----------------
__global__ void k_gcn_xw(const float* __restrict__ nf, const float* __restrict__ w,
                         float* __restrict__ xw) {
    int tid = blockIdx.x * 256 + threadIdx.x;
    int n = tid >> 6, c = tid & 63;
    if (n >= N_NODES) return;
    float s = 0.f;
    #pragma unroll 8
    for (int k = 0; k < F_NODE; ++k) s = fmaf(nf[n * F_NODE + k], w[k * C_GCN + c], s);
    xw[n * C_GCN + c] = s;
}

__global__ void k_deg_init(float* __restrict__ deg) {
    int i = blockIdx.x * 256 + threadIdx.x;
    if (i < N_NODES) deg[i] = 1.0f;   // self loop
}

__global__ void k_deg_count(const int* __restrict__ ei, float* __restrict__ deg) {
    int e = blockIdx.x * 256 + threadIdx.x;
    if (e < N_EDGES) atomicAdd(&deg[ei[N_EDGES + e]], 1.0f);
}

__global__ void k_dinv(const float* __restrict__ deg, float* __restrict__ dinv) {
    int i = blockIdx.x * 256 + threadIdx.x;
    if (i < N_NODES) dinv[i] = rsqrtf(deg[i]);
}

__global__ void k_gcn_self(const float* __restrict__ xw, const float* __restrict__ dinv,
                           const float* __restrict__ gb, float* __restrict__ gout) {
    int tid = blockIdx.x * 256 + threadIdx.x;
    int n = tid >> 6, c = tid & 63;
    if (n >= N_NODES) return;
    float di = dinv[n];
    gout[tid] = xw[tid] * di * di + gb[c];
}

__global__ void k_gcn_scatter(const int* __restrict__ ei, const float* __restrict__ xw,
                              const float* __restrict__ dinv, float* __restrict__ gout) {
    int e = blockIdx.x * 4 + (threadIdx.x >> 6);
    int c = threadIdx.x & 63;
    if (e >= N_EDGES) return;
    int r  = ei[e];
    int cl = ei[N_EDGES + e];
    float nm = dinv[r] * dinv[cl];
    atomicAdd(&gout[cl * C_GCN + c], xw[r * C_GCN + c] * nm);
}

// ---------------- weight packing: wave-major streaming order (round-3 layout) ----------------
__global__ void k_pack(const float* __restrict__ w_ih0, const float* __restrict__ w_hh0,
                       const float* __restrict__ w_ih1, const float* __restrict__ w_hh1,
                       half8* __restrict__ pP) {
    int tid = blockIdx.x * 256 + threadIdx.x;
    if (tid >= 8 * 15 * 4 * 64) return;
    int lane = tid & 63;
    int g    = (tid >> 6) & 3;
    int s    = (tid >> 8) % 15;
    int w    = tid / 3840;
    const float* src; int kt, K;
    if (s < 3)       { src = w_ih0; kt = s;      K = 96;  }
    else if (s < 7)  { src = w_hh0; kt = s - 3;  K = 128; }
    else if (s < 11) { src = w_ih1; kt = s - 7;  K = 128; }
    else             { src = w_hh1; kt = s - 11; K = 128; }
    int row = g * 128 + w * 16 + (lane & 15);
    int k0  = kt * 32 + (lane >> 4) * 8;
    half8 v;
    #pragma unroll
    for (int j = 0; j < 8; ++j) v[j] = (_Float16)src[row * K + k0 + j];
    pP[tid] = v;
}

__global__ void k_bsum(const float* __restrict__ bi0, const float* __restrict__ bh0,
                       const float* __restrict__ bi1, const float* __restrict__ bh1,
                       float* __restrict__ bs) {
    int i = blockIdx.x * 256 + threadIdx.x;
    if (i < 512)       bs[i] = bi0[i] + bh0[i];
    else if (i < 1024) bs[i] = bi1[i - 512] + bh1[i - 512];
}

// ---------------- fused 2-layer LSTM + FC ----------------
// Round-5 pipeline + wave-group slot rotation: waves 0-3 consume slots in the
// canonical order; waves 4-7 consume each phase cyclically rotated (start on
// HH0 / HH1). Waves w and w+4 share a SIMD, so the two resident waves are at
// DIFFERENT pipeline points: one wave's VMW stall / ds_read burst hides under
// the other's MFMA run. Per-wave pipeline shape (and thus all vmcnt counts)
// is identical under rotation. fp32 accumulation order change is harmless.

__device__ __forceinline__ void async_copy16(const void* g, void* l) {
    __builtin_amdgcn_global_load_lds(
        (const __attribute__((address_space(1))) unsigned int*)g,
        (__attribute__((address_space(3))) unsigned int*)l, 16, 0, 0);
}

__device__ __forceinline__ void dma_slot(const char* __restrict__ src, int lane, _Float16* slot) {
    #pragma unroll
    for (int g = 0; g < 4; ++g)
        async_copy16((const void*)(src + g * 1024 + lane * 16), (void*)(slot + g * 512));
}

#define VMW(N) asm volatile("s_waitcnt vmcnt(" #N ")" ::: "memory")

#define BARRIER_NOVM() do {                                   \
    asm volatile("s_waitcnt lgkmcnt(0)" ::: "memory");        \
    __builtin_amdgcn_s_barrier();                             \
    asm volatile("" ::: "memory");                            \
} while (0)

// read 4 B-gate frags of one LDS slot into a register set
#define RDB(BG, BUF) {                                                      \
    _Pragma("unroll")                                                       \
    for (int g = 0; g < 4; ++g) (BG)[g] = *(const half8*)((BUF) + g * 512 + lane * 8); }

// read 3 A frags into a register set
#define RDA(AA, APTR, KOFF, ASTR) {                                         \
    _Pragma("unroll")                                                       \
    for (int mt = 0; mt < MT; ++mt)                                         \
        (AA)[mt] = *(const half8*)((APTR) + (mt * 16 + l15) * (ASTR) + (KOFF) + quad * 8); }

// 12 MFMAs on a loaded set
#define MM(AA, BG) {                                                        \
    _Pragma("unroll")                                                       \
    for (int g = 0; g < 4; ++g)                                             \
        _Pragma("unroll")                                                   \
        for (int mt = 0; mt < MT; ++mt)                                     \
            acc[g][mt] = __builtin_amdgcn_mfma_f32_16x16x32_f16((AA)[mt], (BG)[g], acc[g][mt], 0, 0, 0); }

#define ACCINIT(B) {                                                        \
    _Pragma("unroll")                                                       \
    for (int g = 0; g < 4; ++g) {                                           \
        floatx4 bv = {(B)[g], (B)[g], (B)[g], (B)[g]};                      \
        _Pragma("unroll")                                                   \
        for (int mt = 0; mt < MT; ++mt) acc[g][mt] = bv;                    \
    } }

__device__ __forceinline__ void epilogue(floatx4 acc[4][MT],
                                         float c[MT][4], _Float16* Hnext,
                                         int quad, int ch) {
    #pragma unroll
    for (int mt = 0; mt < MT; ++mt) {
        #pragma unroll
        for (int r = 0; r < 4; ++r) {
            float gi = acc[0][mt][r];
            float gf = acc[1][mt][r];
            float gg = acc[2][mt][r];
            float go = acc[3][mt][r];
            float cn = sigm_f(gf) * c[mt][r] + sigm_f(gi) * tanh_f(gg);
            c[mt][r] = cn;
            float h = sigm_f(go) * tanh_f(cn);
            Hnext[(mt * 16 + quad * 4 + r) * H_STRIDE + ch] = (_Float16)h;
        }
    }
}

__global__ __launch_bounds__(512, 2) void k_lstm(
    const float* __restrict__ seq, const float* __restrict__ gcn,
    const char* __restrict__ pW, const float* __restrict__ bsum,
    const float* __restrict__ fcw, const float* __restrict__ fcb,
    float* __restrict__ out) {

    __shared__ __align__(16) _Float16 sSeq[48 * SEQ_STRIDE];          //  9,984 B
    __shared__ __align__(16) _Float16 sH0[2][48 * H_STRIDE];          // 26,112 B
    __shared__ __align__(16) _Float16 sH1[2][48 * H_STRIDE];          // 26,112 B
    __shared__ __align__(16) _Float16 sWa[8][2048];                   // 32,768 B
    __shared__ __align__(16) _Float16 sWb[8][2048];                   // 32,768 B
    __shared__ __align__(16) _Float16 sWc[8][2048];                   // 32,768 B  total 160,512 B

    const int tid  = threadIdx.x;
    const int wid  = tid >> 6;
    const int lane = tid & 63;
    const int l15  = lane & 15;
    const int quad = lane >> 4;
    const int node0 = blockIdx.x * M_BLK;
    const int ch = wid * 16 + l15;
    const bool rot = (wid >= 4);     // waves 4-7: rotated slot order (pair with 0-3 on SIMDs)

    _Float16* const rb0 = &sWa[wid][0];
    _Float16* const rb1 = &sWb[wid][0];
    _Float16* const rb2 = &sWc[wid][0];

    const char* pWw = pW + wid * WAVE_STREAM;

#define DMA(S, RB) dma_slot(pWw + (S) * 4096, lane, (RB))

    // prologue DMA: first two slots of THIS WAVE'S order in flight during setup
    if (!rot) { DMA(0, rb0); DMA(1, rb1); }
    else      { DMA(3, rb0); DMA(4, rb1); }

    // zero LDS A-buffers (pad rows 40..47 stay zero forever)
    for (int i = tid; i < 48 * SEQ_STRIDE; i += 512) sSeq[i] = (_Float16)0.f;
    for (int i = tid; i < 48 * H_STRIDE; i += 512) {
        sH0[0][i] = (_Float16)0.f; sH0[1][i] = (_Float16)0.f;
        sH1[0][i] = (_Float16)0.f; sH1[1][i] = (_Float16)0.f;
    }

    float bias0[4], bias1[4];
    #pragma unroll
    for (int g = 0; g < 4; ++g) {
        bias0[g] = bsum[g * 128 + ch];
        bias1[g] = bsum[512 + g * 128 + ch];
    }

    float c0[MT][4] = {{0}}, c1[MT][4] = {{0}};

    __syncthreads();   // setup barrier (full drain; prologue DMAs complete here)

    // stage constant gcn columns (32..95) and seq t=0 (cols 0..31)
    for (int i = tid; i < M_BLK * (C_GCN / 2); i += 512) {
        int r = i >> 5, cp = (i & 31) * 2;
        floatx2 v = *(const floatx2*)(gcn + (size_t)(node0 + r) * C_GCN + cp);
        sSeq[r * SEQ_STRIDE + S_SEQ + cp]     = (_Float16)v.x;
        sSeq[r * SEQ_STRIDE + S_SEQ + cp + 1] = (_Float16)v.y;
    }
    {
        int r = tid >> 4, cp = (tid & 15) * 2;
        if (tid < M_BLK * 16) {
            floatx2 v = *(const floatx2*)(seq + ((size_t)(node0 + r) * T_SEQ) * S_SEQ + cp);
            sSeq[r * SEQ_STRIDE + cp]     = (_Float16)v.x;
            sSeq[r * SEQ_STRIDE + cp + 1] = (_Float16)v.y;
        }
    }
    __syncthreads();   // setup barrier (drains; loop counts start from empty queue)

    floatx4 acc[4][MT];
    half8 aX[MT], aY[MT], bX[4], bY[4];

    // preload first B of this wave's order (prologue DMAs drained by syncthreads)
    RDB(bX, rb0);

    // seq prefetch: every wave issues EXACTLY 2 loads per step (uniform vmcnt counts).
    const int pr = tid >> 4, pc = (tid & 15) * 2;
    const int r1 = 32 + ((tid & 127) >> 4);
    floatx2 pfa, pfb;

    if (!rot) {
      // ================== canonical order (waves 0-3) ==================
      for (int t = 0; t < T_SEQ; ++t) {
        const int cur = t & 1, nxt = cur ^ 1;
        const _Float16* h0c = &sH0[cur][0];
        _Float16*       h0n = &sH0[nxt][0];
        const _Float16* h1c = &sH1[cur][0];
        _Float16*       h1n = &sH1[nxt][0];
        {
            int tp = (t + 1 < T_SEQ) ? (t + 1) : (T_SEQ - 1);
            pfa = *(const floatx2*)(seq + ((size_t)(node0 + pr) * T_SEQ + tp) * S_SEQ + pc);
            pfb = *(const floatx2*)(seq + ((size_t)(node0 + r1) * T_SEQ + tp) * S_SEQ + pc);
        }
        // ---- phase A: slots 0..6 (0..2: sSeq x IH0, 3..6: h0c x HH0) ----
        ACCINIT(bias0);
        RDA(aX, sSeq, 0, SEQ_STRIDE);
        DMA(2, rb2);  VMW(6); RDB(bY, rb1); RDA(aY, sSeq, 32, SEQ_STRIDE); MM(aX, bX);
        DMA(3, rb0);  VMW(4); RDB(bX, rb2); RDA(aX, sSeq, 64, SEQ_STRIDE); MM(aY, bY);
        DMA(4, rb1);  VMW(4); RDB(bY, rb0); RDA(aY, h0c, 0,  H_STRIDE);    MM(aX, bX);
        DMA(5, rb2);  VMW(4); RDB(bX, rb1); RDA(aX, h0c, 32, H_STRIDE);    MM(aY, bY);
        DMA(6, rb0);  VMW(4); RDB(bY, rb2); RDA(aY, h0c, 64, H_STRIDE);    MM(aX, bX);
        DMA(7, rb1);  VMW(4); RDB(bX, rb0); RDA(aX, h0c, 96, H_STRIDE);    MM(aY, bY);
        DMA(8, rb2);  VMW(4); RDB(bY, rb1);                                MM(aX, bX);
        epilogue(acc, c0, h0n, quad, ch);
        BARRIER_NOVM();
        // ---- phase B: slots 7..14 (7..10: h0n x IH1, 11..14: h1c x HH1) ----
        ACCINIT(bias1);
        RDA(aY, h0n, 0, H_STRIDE);
        DMA(9,  rb0); VMW(4); RDB(bX, rb2); RDA(aX, h0n, 32, H_STRIDE); MM(aY, bY);
        DMA(10, rb1); VMW(4); RDB(bY, rb0); RDA(aY, h0n, 64, H_STRIDE); MM(aX, bX);
        DMA(11, rb2); VMW(4); RDB(bX, rb1); RDA(aX, h0n, 96, H_STRIDE); MM(aY, bY);
        DMA(12, rb0); VMW(4); RDB(bY, rb2); RDA(aY, h1c, 0,  H_STRIDE); MM(aX, bX);
        DMA(13, rb1); VMW(4); RDB(bX, rb0); RDA(aX, h1c, 32, H_STRIDE); MM(aY, bY);
        DMA(14, rb2); VMW(4); RDB(bY, rb1); RDA(aY, h1c, 64, H_STRIDE); MM(aX, bX);
        DMA(0,  rb0); VMW(4); RDB(bX, rb2); RDA(aX, h1c, 96, H_STRIDE); MM(aY, bY);
        DMA(1,  rb1); VMW(4); MM(aX, bX);   RDB(bX, rb0);
        if (t + 1 < T_SEQ) {
            sSeq[pr * SEQ_STRIDE + pc]     = (_Float16)pfa.x;
            sSeq[pr * SEQ_STRIDE + pc + 1] = (_Float16)pfa.y;
            if (tid < 128) {
                sSeq[r1 * SEQ_STRIDE + pc]     = (_Float16)pfb.x;
                sSeq[r1 * SEQ_STRIDE + pc + 1] = (_Float16)pfb.y;
            }
        }
        epilogue(acc, c1, h1n, quad, ch);
        BARRIER_NOVM();
      }
    } else {
      // ================== rotated order (waves 4-7) ==================
      // phase A order: 3,4,5,6,0,1,2   phase B order: 11,12,13,14,7,8,9,10
      for (int t = 0; t < T_SEQ; ++t) {
        const int cur = t & 1, nxt = cur ^ 1;
        const _Float16* h0c = &sH0[cur][0];
        _Float16*       h0n = &sH0[nxt][0];
        const _Float16* h1c = &sH1[cur][0];
        _Float16*       h1n = &sH1[nxt][0];
        {
            int tp = (t + 1 < T_SEQ) ? (t + 1) : (T_SEQ - 1);
            pfa = *(const floatx2*)(seq + ((size_t)(node0 + pr) * T_SEQ + tp) * S_SEQ + pc);
            pfb = *(const floatx2*)(seq + ((size_t)(node0 + r1) * T_SEQ + tp) * S_SEQ + pc);
        }
        // ---- phase A rotated: HH0 (slots 3..6) then IH0 (slots 0..2) ----
        ACCINIT(bias0);
        RDA(aX, h0c, 0, H_STRIDE);                                          // A(3)
        DMA(5,  rb2); VMW(6); RDB(bY, rb1); RDA(aY, h0c, 32, H_STRIDE);    MM(aX, bX);  // 3
        DMA(6,  rb0); VMW(4); RDB(bX, rb2); RDA(aX, h0c, 64, H_STRIDE);    MM(aY, bY);  // 4
        DMA(0,  rb1); VMW(4); RDB(bY, rb0); RDA(aY, h0c, 96, H_STRIDE);    MM(aX, bX);  // 5
        DMA(1,  rb2); VMW(4); RDB(bX, rb1); RDA(aX, sSeq, 0,  SEQ_STRIDE); MM(aY, bY);  // 6
        DMA(2,  rb0); VMW(4); RDB(bY, rb2); RDA(aY, sSeq, 32, SEQ_STRIDE); MM(aX, bX);  // 0
        DMA(11, rb1); VMW(4); RDB(bX, rb0); RDA(aX, sSeq, 64, SEQ_STRIDE); MM(aY, bY);  // 1
        DMA(12, rb2); VMW(4); RDB(bY, rb1);                                MM(aX, bX);  // 2
        epilogue(acc, c0, h0n, quad, ch);
        BARRIER_NOVM();
        // ---- phase B rotated: HH1 (slots 11..14) then IH1 (slots 7..10) ----
        ACCINIT(bias1);
        RDA(aY, h1c, 0, H_STRIDE);                                          // A(11)
        DMA(13, rb0); VMW(4); RDB(bX, rb2); RDA(aX, h1c, 32, H_STRIDE); MM(aY, bY);  // 11
        DMA(14, rb1); VMW(4); RDB(bY, rb0); RDA(aY, h1c, 64, H_STRIDE); MM(aX, bX);  // 12
        DMA(7,  rb2); VMW(4); RDB(bX, rb1); RDA(aX, h1c, 96, H_STRIDE); MM(aY, bY);  // 13
        DMA(8,  rb0); VMW(4); RDB(bY, rb2); RDA(aY, h0n, 0,  H_STRIDE); MM(aX, bX);  // 14
        DMA(9,  rb1); VMW(4); RDB(bX, rb0); RDA(aX, h0n, 32, H_STRIDE); MM(aY, bY);  // 7
        DMA(10, rb2); VMW(4); RDB(bY, rb1); RDA(aY, h0n, 64, H_STRIDE); MM(aX, bX);  // 8
        DMA(3,  rb0); VMW(4); RDB(bX, rb2); RDA(aX, h0n, 96, H_STRIDE); MM(aY, bY);  // 9
        DMA(4,  rb1); VMW(4); MM(aX, bX);   RDB(bX, rb0);                            // 10 (+preload B(3)')
        if (t + 1 < T_SEQ) {
            sSeq[pr * SEQ_STRIDE + pc]     = (_Float16)pfa.x;
            sSeq[pr * SEQ_STRIDE + pc + 1] = (_Float16)pfa.y;
            if (tid < 128) {
                sSeq[r1 * SEQ_STRIDE + pc]     = (_Float16)pfb.x;
                sSeq[r1 * SEQ_STRIDE + pc + 1] = (_Float16)pfb.y;
            }
        }
        epilogue(acc, c1, h1n, quad, ch);
        BARRIER_NOVM();
      }
    }

#undef DMA

    // drain the tail DMAs (two slots prefetched for the nonexistent step 96)
    asm volatile("s_waitcnt vmcnt(0)" ::: "memory");

    // final h1 lives in buffer (T_SEQ & 1) == 0
    if (tid < M_BLK) {
        const _Float16* h1 = &sH1[0][tid * H_STRIDE];
        float s = fcb[0];
        #pragma unroll 16
        for (int k = 0; k < HID; ++k) s = fmaf((float)h1[k], fcw[k], s);
        out[node0 + tid] = s;
    }
}

// ---------------- launch ----------------
extern "C" void kernel_launch(void* const* d_in, const int* in_sizes, int n_in,
                              void* d_out, int out_size, void* d_ws, size_t ws_size,
                              hipStream_t stream) {
    const float* seq   = (const float*)d_in[0];
    const int*   ei    = (const int*)d_in[1];     // int64 in reference -> int32 on device
    const float* nf    = (const float*)d_in[3];
    const float* gcn_w = (const float*)d_in[5];
    const float* gcn_b = (const float*)d_in[6];
    const float* w_ih0 = (const float*)d_in[7];
    const float* w_hh0 = (const float*)d_in[8];
    const float* b_ih0 = (const float*)d_in[9];
    const float* b_hh0 = (const float*)d_in[10];
    const float* w_ih1 = (const float*)d_in[11];
    const float* w_hh1 = (const float*)d_in[12];
    const float* b_ih1 = (const float*)d_in[13];
    const float* b_hh1 = (const float*)d_in[14];
    const float* fc_w  = (const float*)d_in[15];
    const float* fc_b  = (const float*)d_in[16];
    float* out = (float*)d_out;

    char* ws = (char*)d_ws;
    float* xw   = (float*)(ws);                    // 2,560,000 B
    float* gout = (float*)(ws + 2621440);          // 2,560,000 B
    float* deg  = (float*)(ws + 5242880);          // 40,000 B
    float* dinv = (float*)(ws + 5283840);          // 40,000 B
    float* bsum = (float*)(ws + 5324800);          // 4,096 B
    char*  pP   = (char*)(ws + 5328896);           // 491,520 B

    // GCN (fp32 exact)
    k_gcn_xw     <<<2500,  256, 0, stream>>>(nf, gcn_w, xw);
    k_deg_init   <<<40,    256, 0, stream>>>(deg);
    k_deg_count  <<<625,   256, 0, stream>>>(ei, deg);
    k_dinv       <<<40,    256, 0, stream>>>(deg, dinv);
    k_gcn_self   <<<2500,  256, 0, stream>>>(xw, dinv, gcn_b, gout);
    k_gcn_scatter<<<40000, 256, 0, stream>>>(ei, xw, dinv, gout);

    // weight prep (wave-major streaming layout)
    k_pack<<<120, 256, 0, stream>>>(w_ih0, w_hh0, w_ih1, w_hh1, (half8*)pP);
    k_bsum<<<4,   256, 0, stream>>>(b_ih0, b_hh0, b_ih1, b_hh1, bsum);

    // fused 2-layer LSTM + FC
    k_lstm<<<250, 512, 0, stream>>>(seq, gout, pP, bsum, fc_w, fc_b, out);
}